// Round 1
// baseline (331.768 us; speedup 1.0000x reference)
//
#include <hip/hip_runtime.h>
#include <math.h>

// ---------------------------------------------------------------------------
// EncoderLayer: B=2,S=2048,D=768,H=12,DK=64,DFF=3072
// bf16 MFMA (16x16x32) for all matmuls, fp32 accumulate + fp32 pointwise.
// ---------------------------------------------------------------------------

using bf16   = __bf16;
using bf16x8 = __attribute__((ext_vector_type(8))) __bf16;
using bf16x4 = __attribute__((ext_vector_type(4))) __bf16;
using f32x4  = __attribute__((ext_vector_type(4))) float;

constexpr int S_   = 2048;
constexpr int D_   = 768;
constexpr int H_   = 12;
constexpr int DK_  = 64;
constexpr int DFF_ = 3072;
constexpr int M_   = 4096;   // B*S
constexpr int BH_  = 24;     // B*H

__device__ __forceinline__ f32x4 mfma16(bf16x8 a, bf16x8 b, f32x4 c) {
    return __builtin_amdgcn_mfma_f32_16x16x32_bf16(a, b, c, 0, 0, 0);
}

// ---------------------------------------------------------------------------
// pack x (fp32 -> bf16), 4 elems/thread
// ---------------------------------------------------------------------------
__global__ __launch_bounds__(256)
void pack_x_kernel(const float* __restrict__ x, bf16* __restrict__ xb) {
    const int i = blockIdx.x * 256 + threadIdx.x;
    float4 v = ((const float4*)x)[i];
    bf16x4 o;
    o[0] = (bf16)v.x; o[1] = (bf16)v.y; o[2] = (bf16)v.z; o[3] = (bf16)v.w;
    ((bf16x4*)xb)[i] = o;
}

// ---------------------------------------------------------------------------
// weight transpose+convert: in [K][N] fp32 -> out [N][K] bf16. 64x64 tiles.
// grid = (N/64, K/64), 256 threads.
// ---------------------------------------------------------------------------
__global__ __launch_bounds__(256)
void wt_kernel(const float* __restrict__ in, bf16* __restrict__ out, int K, int N) {
    __shared__ __align__(16) bf16 T[64][72];
    const int n0 = blockIdx.x * 64, k0 = blockIdx.y * 64;
    const int t  = threadIdx.x;
    const int r  = t >> 2, c0 = (t & 3) * 16;
    const float* src = in + (size_t)(k0 + r) * N + n0 + c0;
#pragma unroll
    for (int j = 0; j < 16; j += 4) {
        float4 v = *(const float4*)(src + j);
        T[r][c0 + j + 0] = (bf16)v.x;
        T[r][c0 + j + 1] = (bf16)v.y;
        T[r][c0 + j + 2] = (bf16)v.z;
        T[r][c0 + j + 3] = (bf16)v.w;
    }
    __syncthreads();
    bf16x8 o0, o1;
#pragma unroll
    for (int j = 0; j < 8; j++) { o0[j] = T[c0 + j][r]; o1[j] = T[c0 + 8 + j][r]; }
    bf16* dst = out + (size_t)(n0 + r) * K + k0 + c0;
    *(bf16x8*)(dst)     = o0;
    *(bf16x8*)(dst + 8) = o1;
}

// ---------------------------------------------------------------------------
// Generic 128x128 tile GEMM, C = A[M,K] @ Bt[N,K]^T, bf16 in, fp32 acc.
// 256 threads = 4 waves in 2x2; each wave 64x64 out (4x4 frags of 16x16).
// Reg-staged LDS (single buffer, prefetch next K-tile during MFMA).
// EPI: 0=QKV scatter(+bias), 1=Wo(+bias+resid fp32), 2=FFN1 gelu->bf16,
//      3=FFN2(+bias+resid fp32)
// ---------------------------------------------------------------------------
template<int EPI, int K>
__global__ __launch_bounds__(256)
void gemm_bt(const bf16* __restrict__ A, const bf16* __restrict__ Bt,
             const float* __restrict__ bias0, const float* __restrict__ bias1,
             const float* __restrict__ bias2, const float* __restrict__ resid,
             float* __restrict__ outf, bf16* __restrict__ outb,
             bf16* __restrict__ qo, bf16* __restrict__ ko, bf16* __restrict__ vo) {
    __shared__ __align__(16) bf16 Alds[128 * 64];
    __shared__ __align__(16) bf16 Blds[128 * 64];
    const int tid  = threadIdx.x;
    const int lane = tid & 63, w = tid >> 6;
    const int wm = w >> 1, wn = w & 1;
    const int m0 = blockIdx.y * 128, n0 = blockIdx.x * 128;
    const int g = lane >> 4, q = lane & 15;
    const int lr = lane >> 3, lc = lane & 7;   // staging: row-in-8, 16B chunk

    f32x4 acc[4][4] = {};

    const bf16* ga = A  + (long)(m0 + w * 32 + lr) * K + lc * 8;
    const bf16* gb = Bt + (long)(n0 + w * 32 + lr) * K + lc * 8;
    bf16x8 va[4], vb[4];
#pragma unroll
    for (int i = 0; i < 4; i++) {
        va[i] = *(const bf16x8*)(ga + (long)i * 8 * K);
        vb[i] = *(const bf16x8*)(gb + (long)i * 8 * K);
    }

    for (int kt = 0; kt < K; kt += 64) {
        __syncthreads();
#pragma unroll
        for (int i = 0; i < 4; i++) {
            *(bf16x8*)&Alds[(w * 32 + i * 8 + lr) * 64 + lc * 8] = va[i];
            *(bf16x8*)&Blds[(w * 32 + i * 8 + lr) * 64 + lc * 8] = vb[i];
        }
        __syncthreads();
        if (kt + 64 < K) {
#pragma unroll
            for (int i = 0; i < 4; i++) {
                va[i] = *(const bf16x8*)(ga + (kt + 64) + (long)i * 8 * K);
                vb[i] = *(const bf16x8*)(gb + (kt + 64) + (long)i * 8 * K);
            }
        }
#pragma unroll
        for (int c = 0; c < 2; c++) {
            bf16x8 af[4], bfr[4];
#pragma unroll
            for (int i = 0; i < 4; i++)
                af[i] = *(const bf16x8*)&Alds[(wm * 64 + i * 16 + q) * 64 + c * 32 + g * 8];
#pragma unroll
            for (int i = 0; i < 4; i++)
                bfr[i] = *(const bf16x8*)&Blds[(wn * 64 + i * 16 + q) * 64 + c * 32 + g * 8];
#pragma unroll
            for (int mi = 0; mi < 4; mi++)
#pragma unroll
                for (int ni = 0; ni < 4; ni++)
                    acc[mi][ni] = mfma16(af[mi], bfr[ni], acc[mi][ni]);
        }
    }

    // epilogue: C/D frag layout col = lane&15, row = (lane>>4)*4 + r
#pragma unroll
    for (int mi = 0; mi < 4; mi++) {
#pragma unroll
        for (int ni = 0; ni < 4; ni++) {
            const int col = n0 + wn * 64 + ni * 16 + q;
            float bias;
            int which = 0, dd = col;
            if (EPI == 0) {
                which = (col >= 1536) ? 2 : (col >= 768 ? 1 : 0);
                dd    = col - which * 768;
                bias  = (which == 0 ? bias0 : which == 1 ? bias1 : bias2)[dd];
            } else {
                bias = bias0[col];
            }
#pragma unroll
            for (int r = 0; r < 4; r++) {
                const int row = m0 + wm * 64 + mi * 16 + g * 4 + r;
                float v = acc[mi][ni][r] + bias;
                if (EPI == 0) {
                    // scatter to [bh][s][dk] (bh = b*12 + h)
                    bf16* dst = (which == 0) ? qo : (which == 1) ? ko : vo;
                    const int hh = dd >> 6, dk = dd & 63;
                    dst[(((long)(row >> 11) * 12 + hh) * 2048 + (row & 2047)) * 64 + dk] = (bf16)v;
                } else if (EPI == 1 || EPI == 3) {
                    outf[(long)row * 768 + col] = v + resid[(long)row * 768 + col];
                } else { // EPI == 2: exact GELU -> bf16
                    float gl = 0.5f * v * (1.0f + erff(v * 0.70710678118654752f));
                    outb[(long)row * 3072 + col] = (bf16)gl;
                }
            }
        }
    }
}

// ---------------------------------------------------------------------------
// per-(head,row) L2 normalize of Q and K in place. One wave per 64-elem row.
// ---------------------------------------------------------------------------
__global__ __launch_bounds__(256)
void norm_qk_kernel(bf16* __restrict__ Q, bf16* __restrict__ K) {
    const int wid  = blockIdx.x * 4 + (threadIdx.x >> 6);
    const int lane = threadIdx.x & 63;
    bf16* buf = (wid < BH_ * S_) ? Q : K;
    const int row = (wid < BH_ * S_) ? wid : wid - BH_ * S_;
    bf16* ptr = buf + (long)row * 64 + lane;
    float v  = (float)*ptr;
    float ss = v * v;
#pragma unroll
    for (int o = 32; o; o >>= 1) ss += __shfl_xor(ss, o);
    float n = sqrtf(ss);
    *ptr = (bf16)(v / fmaxf(n, 1e-12f));
}

// ---------------------------------------------------------------------------
// V transpose: [bh][2048][64] -> Vt [bh][64][2048]
// ---------------------------------------------------------------------------
__global__ __launch_bounds__(256)
void transpose_v_kernel(const bf16* __restrict__ V, bf16* __restrict__ Vt) {
    __shared__ __align__(16) bf16 T[64][72];
    const int bh = blockIdx.y, s0 = blockIdx.x * 64;
    const int t = threadIdx.x;
    const int r = t >> 2, c0 = (t & 3) * 16;
    const bf16* src = V + ((long)bh * S_ + s0) * 64;
    *(bf16x8*)&T[r][c0]     = *(const bf16x8*)&src[r * 64 + c0];
    *(bf16x8*)&T[r][c0 + 8] = *(const bf16x8*)&src[r * 64 + c0 + 8];
    __syncthreads();
    bf16x8 o0, o1;
#pragma unroll
    for (int j = 0; j < 8; j++) { o0[j] = T[c0 + j][r]; o1[j] = T[c0 + 8 + j][r]; }
    bf16* dst = Vt + ((long)bh * 64 + r) * S_ + s0 + c0;
    *(bf16x8*)(dst)     = o0;
    *(bf16x8*)(dst + 8) = o1;
}

// ---------------------------------------------------------------------------
// Attention (no softmax): O = (Qn Kn^T)^2 @ V  per (b,h).
// Block = 128 q-rows, 4 waves x 32 rows; 64-key tiles.
// P (=S^2, bf16) round-trips through wave-private padded LDS to become the
// PV A-fragment. V consumed via Vt so B-frags are contiguous 16B loads.
// ---------------------------------------------------------------------------
__global__ __launch_bounds__(256)
void attn_kernel(const bf16* __restrict__ Qn, const bf16* __restrict__ Kn,
                 const bf16* __restrict__ Vt, bf16* __restrict__ AO) {
    const int bh   = blockIdx.y;
    const int tid  = threadIdx.x, lane = tid & 63, w = tid >> 6;
    const int g = lane >> 4, q = lane & 15;
    const int qbase = blockIdx.x * 128 + w * 32;
    __shared__ __align__(16) bf16 P[4][32][72];

    const bf16* Qp = Qn + (long)bh * S_ * 64;
    const bf16* Kp = Kn + (long)bh * S_ * 64;
    const bf16* Vp = Vt + (long)bh * 64 * S_;

    bf16x8 qf[2][2];
#pragma unroll
    for (int mi = 0; mi < 2; mi++)
#pragma unroll
        for (int c = 0; c < 2; c++)
            qf[mi][c] = *(const bf16x8*)&Qp[(long)(qbase + mi * 16 + q) * 64 + c * 32 + g * 8];

    f32x4 o[2][4] = {};

    for (int kt = 0; kt < S_; kt += 64) {
        bf16x8 kf[4][2];
#pragma unroll
        for (int ni = 0; ni < 4; ni++)
#pragma unroll
            for (int c = 0; c < 2; c++)
                kf[ni][c] = *(const bf16x8*)&Kp[(long)(kt + ni * 16 + q) * 64 + c * 32 + g * 8];
#pragma unroll
        for (int mi = 0; mi < 2; mi++)
#pragma unroll
            for (int ni = 0; ni < 4; ni++) {
                f32x4 s = {};
                s = mfma16(qf[mi][0], kf[ni][0], s);
                s = mfma16(qf[mi][1], kf[ni][1], s);
#pragma unroll
                for (int r = 0; r < 4; r++) {
                    float p = s[r] * s[r];
                    P[w][mi * 16 + g * 4 + r][ni * 16 + q] = (bf16)p;
                }
            }
        __syncthreads();
        bf16x8 pf[2][2], vf[4][2];
#pragma unroll
        for (int mi = 0; mi < 2; mi++)
#pragma unroll
            for (int c = 0; c < 2; c++)
                pf[mi][c] = *(const bf16x8*)&P[w][mi * 16 + q][c * 32 + g * 8];
#pragma unroll
        for (int ni = 0; ni < 4; ni++)
#pragma unroll
            for (int c = 0; c < 2; c++)
                vf[ni][c] = *(const bf16x8*)&Vp[(long)(ni * 16 + q) * S_ + kt + c * 32 + g * 8];
#pragma unroll
        for (int mi = 0; mi < 2; mi++)
#pragma unroll
            for (int ni = 0; ni < 4; ni++) {
                o[mi][ni] = mfma16(pf[mi][0], vf[ni][0], o[mi][ni]);
                o[mi][ni] = mfma16(pf[mi][1], vf[ni][1], o[mi][ni]);
            }
        __syncthreads();
    }

    const int b = bh / 12, h = bh % 12;
#pragma unroll
    for (int mi = 0; mi < 2; mi++)
#pragma unroll
        for (int ni = 0; ni < 4; ni++)
#pragma unroll
            for (int r = 0; r < 4; r++) {
                int s = qbase + mi * 16 + g * 4 + r;
                int d = ni * 16 + q;
                AO[((long)b * S_ + s) * D_ + h * 64 + d] = (bf16)o[mi][ni][r];
            }
}

// ---------------------------------------------------------------------------
// LayerNorm over D=768. One block per row, 256 threads (3 elems each).
// ---------------------------------------------------------------------------
template<bool WB>
__global__ __launch_bounds__(256)
void ln_kernel(const float* __restrict__ y, const float* __restrict__ gamma,
               const float* __restrict__ beta, float* __restrict__ xo,
               bf16* __restrict__ xob) {
    __shared__ float sa[4], sb[4];
    const int row = blockIdx.x, t = threadIdx.x;
    const float* yr = y + (long)row * 768;
    float v0 = yr[t], v1 = yr[t + 256], v2 = yr[t + 512];
    float s  = v0 + v1 + v2;
    float ss = v0 * v0 + v1 * v1 + v2 * v2;
#pragma unroll
    for (int o = 32; o; o >>= 1) { s += __shfl_xor(s, o); ss += __shfl_xor(ss, o); }
    if ((t & 63) == 0) { sa[t >> 6] = s; sb[t >> 6] = ss; }
    __syncthreads();
    s  = sa[0] + sa[1] + sa[2] + sa[3];
    ss = sb[0] + sb[1] + sb[2] + sb[3];
    const float mu   = s * (1.0f / 768.0f);
    const float var  = ss * (1.0f / 768.0f) - mu * mu;
    const float rstd = rsqrtf(var + 1e-5f);
    float* xr = xo + (long)row * 768;
#pragma unroll
    for (int i = 0; i < 3; i++) {
        const int c = t + i * 256;
        const float vv = (i == 0) ? v0 : (i == 1) ? v1 : v2;
        const float ov = (vv - mu) * rstd * gamma[c] + beta[c];
        xr[c] = ov;
        if (WB) xob[(long)row * 768 + c] = (bf16)ov;
    }
}

// ---------------------------------------------------------------------------
extern "C" void kernel_launch(void* const* d_in, const int* in_sizes, int n_in,
                              void* d_out, int out_size, void* d_ws, size_t ws_size,
                              hipStream_t stream) {
    const float* x     = (const float*)d_in[0];
    const float* Wq    = (const float*)d_in[1];
    const float* bq    = (const float*)d_in[2];
    const float* Wk    = (const float*)d_in[3];
    const float* bk    = (const float*)d_in[4];
    const float* Wv    = (const float*)d_in[5];
    const float* bv    = (const float*)d_in[6];
    const float* Wo    = (const float*)d_in[7];
    const float* bo    = (const float*)d_in[8];
    const float* W1    = (const float*)d_in[9];
    const float* b1    = (const float*)d_in[10];
    const float* W2    = (const float*)d_in[11];
    const float* b2    = (const float*)d_in[12];
    const float* gamma = (const float*)d_in[13];
    const float* beta  = (const float*)d_in[14];

    char* p = (char*)d_ws;
    auto alloc = [&](size_t bytes) -> void* {
        void* r = p;
        p += (bytes + 255) & ~(size_t)255;
        return r;
    };
    bf16*  Xb    = (bf16*)alloc((size_t)M_ * D_ * 2);
    bf16*  Wqkvt = (bf16*)alloc((size_t)2304 * 768 * 2);
    bf16*  Wot   = (bf16*)alloc((size_t)768 * 768 * 2);
    bf16*  W1t   = (bf16*)alloc((size_t)3072 * 768 * 2);
    bf16*  W2t   = (bf16*)alloc((size_t)768 * 3072 * 2);
    bf16*  Qh    = (bf16*)alloc((size_t)BH_ * S_ * DK_ * 2);
    bf16*  Kh    = (bf16*)alloc((size_t)BH_ * S_ * DK_ * 2);
    bf16*  Vh    = (bf16*)alloc((size_t)BH_ * S_ * DK_ * 2);
    bf16*  Vt    = (bf16*)alloc((size_t)BH_ * S_ * DK_ * 2);
    bf16*  AO    = (bf16*)alloc((size_t)M_ * D_ * 2);
    float* y1    = (float*)alloc((size_t)M_ * D_ * 4);
    float* x1    = (float*)alloc((size_t)M_ * D_ * 4);
    bf16*  x1b   = (bf16*)alloc((size_t)M_ * D_ * 2);
    bf16*  hbuf  = (bf16*)alloc((size_t)M_ * DFF_ * 2);
    float* y2    = y1;  // y1 dead after LN1

    // pack + transpose weights
    pack_x_kernel<<<(M_ * D_) / 1024, 256, 0, stream>>>(x, Xb);
    wt_kernel<<<dim3(12, 12), 256, 0, stream>>>(Wq, Wqkvt,             768, 768);
    wt_kernel<<<dim3(12, 12), 256, 0, stream>>>(Wk, Wqkvt + 768 * 768, 768, 768);
    wt_kernel<<<dim3(12, 12), 256, 0, stream>>>(Wv, Wqkvt + 1536 * 768, 768, 768);
    wt_kernel<<<dim3(12, 12), 256, 0, stream>>>(Wo, Wot, 768, 768);
    wt_kernel<<<dim3(48, 12), 256, 0, stream>>>(W1, W1t, 768, 3072);
    wt_kernel<<<dim3(12, 48), 256, 0, stream>>>(W2, W2t, 3072, 768);

    // QKV projection -> [bh][s][dk] bf16
    gemm_bt<0, 768><<<dim3(18, 32), 256, 0, stream>>>(
        Xb, Wqkvt, bq, bk, bv, nullptr, nullptr, nullptr, Qh, Kh, Vh);
    norm_qk_kernel<<<(2 * BH_ * S_) / 4, 256, 0, stream>>>(Qh, Kh);
    transpose_v_kernel<<<dim3(S_ / 64, BH_), 256, 0, stream>>>(Vh, Vt);

    // attention
    attn_kernel<<<dim3(S_ / 128, BH_), 256, 0, stream>>>(Qh, Kh, Vt, AO);

    // out projection + residual, LN1
    gemm_bt<1, 768><<<dim3(6, 32), 256, 0, stream>>>(
        AO, Wot, bo, nullptr, nullptr, x, y1, nullptr, nullptr, nullptr, nullptr);
    ln_kernel<true><<<M_, 256, 0, stream>>>(y1, gamma, beta, x1, x1b);

    // FFN
    gemm_bt<2, 768><<<dim3(24, 32), 256, 0, stream>>>(
        x1b, W1t, b1, nullptr, nullptr, nullptr, nullptr, hbuf, nullptr, nullptr, nullptr);
    gemm_bt<3, 3072><<<dim3(6, 32), 256, 0, stream>>>(
        hbuf, W2t, b2, nullptr, nullptr, x1, y2, nullptr, nullptr, nullptr, nullptr);
    ln_kernel<false><<<M_, 256, 0, stream>>>(y2, gamma, beta, (float*)d_out, nullptr);
}